// Round 13
// baseline (235.356 us; speedup 1.0000x reference)
//
#include <hip/hip_runtime.h>

// out[b,h,w,u] = sum_d (w[u,d] - x[b,h,w,d])^2 = ||x||^2 - 2 x.w + ||w||^2
// x: [524288, 64] fp32 (134 MB read once), w: [64,64] fp32 (16 KB),
// out: [524288, 64] fp32 (134 MB written once). Memory-bound.
//
// Ladder:
// R1: spill traffic flows at 5.3 TB/s marginal -> pipes have headroom.
// R2: wave count null. R3: +1 tile in flight +9%. R4: compiler sinks reg
//     pipelines. R5/R10: LDS-DMA pipelines null. R6: full-line stores null.
// R7-R9: no-allocate STORES incompatible with harness memset-through-cache.
// R11: unambiguous depth-3 asm register pipeline -> still 81.6us.
// R12: sc0 (L1 bypass) on reads -> flat. Nine structurally distinct kernels
//     all land at 82+-3us; read stream pinned at ~1.65 TB/s effective.
// R13: MALL-churn model: per dispatch we ALLOCATE 268MB (134 X read-alloc +
//     134 Out write-alloc) into the 256MB MALL = 100% churn; read-allocs
//     cost the fill port twice (miss-fetch + fill). Port demand ~4.9 TB/s ==
//     the same budget the harness fill saturates (6.4 TB/s pure writes).
//     A port-serialized cache explains why ALL concurrency levers were null
//     (even fully-serial R0 runs at the same 82us). The one untested lever:
//     NON-TEMPORAL READS (no round ever set nt on loads). "sc0 nt" = bypass
//     L1 + no-allocate stream: X stops churning the MALL, halving alloc-port
//     demand. FETCH will rise toward 134MB (give up cross-dispatch hits;
//     HBM has 4 TB/s headroom). Model right -> 55-70us. Flat/worse -> revert
//     to R11 and declare roofline.

typedef float  float4v  __attribute__((ext_vector_type(4)));
typedef __bf16 bf16x8   __attribute__((ext_vector_type(8)));

static constexpr int kRows  = 16 * 128 * 256;   // 524288
static constexpr int kTiles = kRows / 16;       // 32768
static constexpr int kWaves = 1024 * 4;         // grid fixed: 1024 blocks x 4 waves
static constexpr int kIters = kTiles / kWaves;  // 8, exact

__device__ __forceinline__ bf16x8 cvt2(float4v a, float4v b) {
  bf16x8 r;
  r[0] = (__bf16)a[0]; r[1] = (__bf16)a[1]; r[2] = (__bf16)a[2]; r[3] = (__bf16)a[3];
  r[4] = (__bf16)b[0]; r[5] = (__bf16)b[1]; r[6] = (__bf16)b[2]; r[7] = (__bf16)b[3];
  return r;
}

// Issue tile t's 4 lane-fragment loads into a named register slot.
// sc0 nt = L1-bypass + NO-ALLOCATE streaming read (the R13 experiment).
// Lane (q,m) reads row (t*16+m), floats [8q..8q+7], [32+8q..32+8q+7].
// Volatile asm: cannot be sunk or reordered; early-clobber keeps dests
// disjoint from address operands. Loads are correctness-neutral w.r.t.
// cache policy - rest of kernel byte-identical to passing R12.
#define ISSUE(s0v, s1v, s2v, s3v, t)                                          \
  do {                                                                        \
    const float* p_ = X + (size_t)((t) * 16 + m) * 64 + q * 8;                \
    asm volatile("global_load_dwordx4 %0, %4, off sc0 nt\n\t"                 \
                 "global_load_dwordx4 %1, %5, off sc0 nt\n\t"                 \
                 "global_load_dwordx4 %2, %6, off sc0 nt\n\t"                 \
                 "global_load_dwordx4 %3, %7, off sc0 nt"                     \
                 : "=&v"(s0v), "=&v"(s1v), "=&v"(s2v), "=&v"(s3v)             \
                 : "v"(p_), "v"(p_ + 4), "v"(p_ + 32), "v"(p_ + 36));         \
  } while (0)

// Wait until tile's loads returned. N = count of YOUNGER LOADS only
// (loads retire in order among themselves; interleaved stores only make the
// wait stricter -> safe under out-of-order store retirement). The "+v" ties
// make every later use of the slot data-depend on this wait.
#define WAITC(Nstr, s0v, s1v, s2v, s3v)                                       \
  asm volatile("s_waitcnt vmcnt(" Nstr ")"                                    \
               : "+v"(s0v), "+v"(s1v), "+v"(s2v), "+v"(s3v)::"memory")

__global__ __launch_bounds__(256) void sqdist_kernel(
    const float* __restrict__ X, const float* __restrict__ W,
    float* __restrict__ Out) {
  const int lane = threadIdx.x & 63;
  const int wid  = threadIdx.x >> 6;
  const int q    = lane >> 4;   // quad 0..3
  const int m    = lane & 15;

  // ---- Setup: w fragments (A operand) + redistributed ||w||^2 ----
  bf16x8 aw[4][2];
  float  w2adj[4][4];  // [ut][reg]: ||w_u||^2 for u = 16*ut + q*4 + reg
#pragma unroll
  for (int ut = 0; ut < 4; ++ut) {
    const float4v* wr = (const float4v*)(W + (ut * 16 + m) * 64);
    float4v v0 = wr[q * 2];
    float4v v1 = wr[q * 2 + 1];
    float4v v2 = wr[8 + q * 2];
    float4v v3 = wr[8 + q * 2 + 1];
    aw[ut][0] = cvt2(v0, v1);
    aw[ut][1] = cvt2(v2, v3);
    float s = 0.f;
#pragma unroll
    for (int i = 0; i < 4; ++i)
      s += v0[i] * v0[i] + v1[i] * v1[i] + v2[i] * v2[i] + v3[i] * v3[i];
    s += __shfl_xor(s, 16);
    s += __shfl_xor(s, 32);
#pragma unroll
    for (int r = 0; r < 4; ++r)
      w2adj[ut][r] = __shfl(s, q * 4 + r);
  }

  const int gw = blockIdx.x * 4 + wid;  // wave id 0..4095; 8 tiles/wave

  // Consume one tile held in registers: norm, cvt, 8 MFMAs, plain stores
  // (compiler-visible stores -> auto-waited, endpgm-safe).
  auto consume = [&](float4v x0, float4v x1, float4v x2, float4v x3, int t) {
    float s = 0.f;
#pragma unroll
    for (int i = 0; i < 4; ++i)
      s += x0[i] * x0[i] + x1[i] * x1[i] + x2[i] * x2[i] + x3[i] * x3[i];
    s += __shfl_xor(s, 16);
    s += __shfl_xor(s, 32);      // s = ||x_(t*16+m)||^2 (C-col of lane = m)

    bf16x8 bx0 = cvt2(x0, x1);
    bf16x8 bx1 = cvt2(x2, x3);

    float4v acc[4];
#pragma unroll
    for (int ut = 0; ut < 4; ++ut) {
      float4v z = {0.f, 0.f, 0.f, 0.f};
      acc[ut] = __builtin_amdgcn_mfma_f32_16x16x32_bf16(aw[ut][0], bx0, z, 0, 0, 0);
      acc[ut] = __builtin_amdgcn_mfma_f32_16x16x32_bf16(aw[ut][1], bx1, acc[ut], 0, 0, 0);
    }

    float4v* orow = (float4v*)(Out + (size_t)(t * 16 + m) * 64);
#pragma unroll
    for (int ut = 0; ut < 4; ++ut) {
      float4v o;
#pragma unroll
      for (int r = 0; r < 4; ++r)
        o[r] = fmaf(-2.f, acc[ut][r], s + w2adj[ut][r]);
      orow[ut * 4 + q] = o;   // floats [16*ut + 4*q .. +3] of this row
    }
  };

  // ---- Depth-3 register pipeline over exactly 8 tiles, hand-unrolled ----
  float4v A0, A1, A2, A3, B0, B1, B2, B3, C0, C1, C2, C3;

  ISSUE(A0, A1, A2, A3, gw + 0 * kWaves);
  ISSUE(B0, B1, B2, B3, gw + 1 * kWaves);
  ISSUE(C0, C1, C2, C3, gw + 2 * kWaves);

  WAITC("8", A0, A1, A2, A3);  consume(A0, A1, A2, A3, gw + 0 * kWaves);
  ISSUE(A0, A1, A2, A3, gw + 3 * kWaves);

  WAITC("8", B0, B1, B2, B3);  consume(B0, B1, B2, B3, gw + 1 * kWaves);
  ISSUE(B0, B1, B2, B3, gw + 4 * kWaves);

  WAITC("8", C0, C1, C2, C3);  consume(C0, C1, C2, C3, gw + 2 * kWaves);
  ISSUE(C0, C1, C2, C3, gw + 5 * kWaves);

  WAITC("8", A0, A1, A2, A3);  consume(A0, A1, A2, A3, gw + 3 * kWaves);
  ISSUE(A0, A1, A2, A3, gw + 6 * kWaves);

  WAITC("8", B0, B1, B2, B3);  consume(B0, B1, B2, B3, gw + 4 * kWaves);
  ISSUE(B0, B1, B2, B3, gw + 7 * kWaves);

  WAITC("8", C0, C1, C2, C3);  consume(C0, C1, C2, C3, gw + 5 * kWaves);

  WAITC("4", A0, A1, A2, A3);  consume(A0, A1, A2, A3, gw + 6 * kWaves);

  WAITC("0", B0, B1, B2, B3);  consume(B0, B1, B2, B3, gw + 7 * kWaves);
}

extern "C" void kernel_launch(void* const* d_in, const int* in_sizes, int n_in,
                              void* d_out, int out_size, void* d_ws, size_t ws_size,
                              hipStream_t stream) {
  const float* X = (const float*)d_in[0];
  const float* W = (const float*)d_in[1];
  float* Out = (float*)d_out;
  // 1024 blocks x 256 (4 waves) = 4096 waves; 8 tiles/wave, depth-3 asm
  // register pipeline with sc0+nt (L1-bypass, MALL-no-allocate) streaming reads.
  sqdist_kernel<<<1024, 256, 0, stream>>>(X, W, Out);
}